// Round 1
// baseline (323.167 us; speedup 1.0000x reference)
//
#include <hip/hip_runtime.h>
#include <hip/hip_bf16.h>

#define N_FINE   16384
#define S_COARSE 4096
#define DC       256
#define DF       64
#define K1       320   // DC + DF
#define C1       256
#define C2       128
#define BIGF     1e8f
#define EPS_W    1e-8f
#define EPS_BN   1e-5f

// ---------------- workspace layout (bytes) ----------------
// all offsets 16B aligned
#define OFF_RANGES 0          // 8 ints: start[4], end[4]
#define OFF_SUMS   256        // sums1[256] sumsq1[256] sums2[128] sumsq2[128] = 768 f
#define OFF_SCALE1 3328       // 256 f
#define OFF_SHIFT1 4352       // 256 f
#define OFF_SCALE2 5376       // 128 f
#define OFF_SHIFT2 5888       // 128 f
#define OFF_CPACK  8192       // 4096 * float4 = 64 KiB
#define OFF_CFT    73728      // 4096*256*4 = 4 MiB
#define OFF_IDX3   4268032    // 16384*3 int
#define OFF_W3     4464640    // 16384*3 f
#define OFF_XCAT   4661248    // 16384*320*4 = 20 MiB
#define OFF_Y1     25632768   // 16384*256*4 = 16 MiB
#define OFF_Y2     42409984   // 16384*128*4 = 8 MiB

// ---------------- piece ranges ----------------
__global__ __launch_bounds__(256) void range_kernel(const int* __restrict__ cid,
                                                    int* __restrict__ ranges) {
    int t = threadIdx.x;
    if (t < 8) ranges[t] = 0;
    __syncthreads();
    for (int s = t; s < S_COARSE; s += 256) {
        int c = cid[s];
        if (s == 0 || cid[s - 1] != c) ranges[c] = s;          // start
        if (s == S_COARSE - 1 || cid[s + 1] != c) ranges[4 + c] = s + 1; // end
    }
}

// ---------------- pack coarse xyz + |c|^2 ----------------
__global__ __launch_bounds__(256) void pack_coarse_kernel(const float* __restrict__ cxyz,
                                                          float4* __restrict__ cpack) {
    int s = blockIdx.x * 256 + threadIdx.x;
    float x = cxyz[s], y = cxyz[S_COARSE + s], z = cxyz[2 * S_COARSE + s];
    cpack[s] = make_float4(x, y, z, x * x + y * y + z * z);
}

// ---------------- transpose coarse features [256][4096] -> [4096][256] ----------------
__global__ __launch_bounds__(256) void transpose_cf_kernel(const float* __restrict__ cf,
                                                           float* __restrict__ cfT) {
    __shared__ float tile[32][33];
    int tx = threadIdx.x & 31, ty = threadIdx.x >> 5;  // ty 0..7
    int s0 = blockIdx.x * 32, c0 = blockIdx.y * 32;
    #pragma unroll
    for (int i = 0; i < 4; i++) {
        int c = c0 + ty + i * 8;
        tile[ty + i * 8][tx] = cf[c * S_COARSE + s0 + tx];
    }
    __syncthreads();
    #pragma unroll
    for (int i = 0; i < 4; i++) {
        int s = ty + i * 8;
        cfT[(s0 + s) * DC + c0 + tx] = tile[tx][s];
    }
}

// ---------------- 3-NN within piece range + IDW weights ----------------
// block = 256 threads = 16 points x 16 chunks (contiguous subranges -> stable ties)
__global__ __launch_bounds__(256) void knn_kernel(const float* __restrict__ fxyz,
                                                  const int* __restrict__ fpid,
                                                  const float4* __restrict__ cpack,
                                                  const int* __restrict__ ranges,
                                                  int* __restrict__ idx3,
                                                  float* __restrict__ w3) {
    __shared__ float md[16][16][3];
    __shared__ int   mi[16][16][3];
    int t = threadIdx.x;
    int p = t & 15, ch = t >> 4;
    int n = blockIdx.x * 16 + p;
    int fid = fpid[n];
    float fx = fxyz[n], fy = fxyz[N_FINE + n], fz = fxyz[2 * N_FINE + n];
    float fn2 = fx * fx + fy * fy + fz * fz;
    int st = ranges[fid], en = ranges[4 + fid];
    int cnt = en - st;
    int L = (cnt + 15) >> 4;
    int cs = st + ch * L;
    int ce = min(cs + L, en);
    float d0 = BIGF, d1 = BIGF, d2v = BIGF;
    int i0 = -1, i1 = -1, i2 = -1;
    for (int s = cs; s < ce; ++s) {
        float4 c = cpack[s];
        float d = fn2 + c.w - 2.0f * (fx * c.x + fy * c.y + fz * c.z);
        if (d < d0)       { d2v = d1; i2 = i1; d1 = d0; i1 = i0; d0 = d; i0 = s; }
        else if (d < d1)  { d2v = d1; i2 = i1; d1 = d;  i1 = s; }
        else if (d < d2v) { d2v = d;  i2 = s; }
    }
    md[p][ch][0] = d0;  md[p][ch][1] = d1;  md[p][ch][2] = d2v;
    mi[p][ch][0] = i0;  mi[p][ch][1] = i1;  mi[p][ch][2] = i2;
    __syncthreads();
    if (t < 16) {
        // p == t here, so n/st/en above are for point t.
        d0 = d1 = d2v = BIGF; i0 = i1 = i2 = -1;
        for (int c = 0; c < 16; c++) {
            #pragma unroll
            for (int k = 0; k < 3; k++) {
                int ii = mi[t][c][k];
                if (ii < 0) continue;
                float d = md[t][c][k];
                if (d < d0)       { d2v = d1; i2 = i1; d1 = d0; i1 = i0; d0 = d; i0 = ii; }
                else if (d < d1)  { d2v = d1; i2 = i1; d1 = d;  i1 = ii; }
                else if (d < d2v) { d2v = d;  i2 = ii; }
            }
        }
        // fewer than 3 in-piece candidates: fill with lowest masked indices (all BIG),
        // matching top_k stability on the all-BIG masked row.
        int cand = 0;
        while (i0 < 0 || i1 < 0 || i2 < 0) {
            if (cand >= st && cand < en) { cand = en; continue; }
            if (i0 < 0)      { i0 = cand; d0 = BIGF; }
            else if (i1 < 0) { i1 = cand; d1 = BIGF; }
            else             { i2 = cand; d2v = BIGF; }
            cand++;
        }
        float w0 = 1.0f / (d0 + EPS_W);
        float w1 = 1.0f / (d1 + EPS_W);
        float w2 = 1.0f / (d2v + EPS_W);
        float inv = 1.0f / (w0 + w1 + w2);
        idx3[n * 3 + 0] = i0; idx3[n * 3 + 1] = i1; idx3[n * 3 + 2] = i2;
        w3[n * 3 + 0] = w0 * inv; w3[n * 3 + 1] = w1 * inv; w3[n * 3 + 2] = w2 * inv;
    }
}

// ---------------- build x = [interp(256) | fine_feat(64)] row-major [N][320] ----------------
__global__ __launch_bounds__(256) void build_x_kernel(const int* __restrict__ idx3,
                                                      const float* __restrict__ w3,
                                                      const float* __restrict__ cfT,
                                                      const float* __restrict__ ff,
                                                      float* __restrict__ X) {
    int n = blockIdx.x, t = threadIdx.x;
    int i0 = idx3[n * 3], i1 = idx3[n * 3 + 1], i2 = idx3[n * 3 + 2];
    float w0 = w3[n * 3], w1 = w3[n * 3 + 1], w2 = w3[n * 3 + 2];
    float v = w0 * cfT[i0 * DC + t] + w1 * cfT[i1 * DC + t] + w2 * cfT[i2 * DC + t];
    X[n * K1 + t] = v;
    if (t < DF) X[n * K1 + DC + t] = ff[t * N_FINE + n];
}

// ---------------- tiled f32 GEMM: Y[m][j] = dot(A[m][:K], W[j][:K]) + bias[j] ----------------
// BM=BN=64, BK=32, 256 threads, 4x4 micro-tile. Optional fused BN+ReLU on A load.
template <int KDIM, int NOUT, bool BN_IN>
__global__ __launch_bounds__(256) void gemm_kernel(const float* __restrict__ A,
                                                   const float* __restrict__ W,
                                                   const float* __restrict__ bias,
                                                   const float* __restrict__ scale,
                                                   const float* __restrict__ shift,
                                                   float* __restrict__ Y) {
    __shared__ float As[32][64];
    __shared__ float Bs[32][64];
    int t = threadIdx.x;
    int m0 = blockIdx.x * 64, j0 = blockIdx.y * 64;
    int row = t >> 3, q = t & 7;          // staging: row 0..31, q 0..7 (float4 along K)
    int tm = (t & 15) * 4, tn = (t >> 4) * 4;
    float acc[4][4] = {};
    for (int kt = 0; kt < KDIM; kt += 32) {
        float4 a0 = *(const float4*)&A[(m0 + row) * KDIM + kt + q * 4];
        float4 a1 = *(const float4*)&A[(m0 + row + 32) * KDIM + kt + q * 4];
        float4 b0 = *(const float4*)&W[(j0 + row) * KDIM + kt + q * 4];
        float4 b1v = *(const float4*)&W[(j0 + row + 32) * KDIM + kt + q * 4];
        if (BN_IN) {
            float4 s4 = *(const float4*)&scale[kt + q * 4];
            float4 h4 = *(const float4*)&shift[kt + q * 4];
            a0.x = fmaxf(fmaf(a0.x, s4.x, h4.x), 0.f);
            a0.y = fmaxf(fmaf(a0.y, s4.y, h4.y), 0.f);
            a0.z = fmaxf(fmaf(a0.z, s4.z, h4.z), 0.f);
            a0.w = fmaxf(fmaf(a0.w, s4.w, h4.w), 0.f);
            a1.x = fmaxf(fmaf(a1.x, s4.x, h4.x), 0.f);
            a1.y = fmaxf(fmaf(a1.y, s4.y, h4.y), 0.f);
            a1.z = fmaxf(fmaf(a1.z, s4.z, h4.z), 0.f);
            a1.w = fmaxf(fmaf(a1.w, s4.w, h4.w), 0.f);
        }
        __syncthreads();   // previous iteration's reads done before overwrite
        As[q * 4 + 0][row] = a0.x; As[q * 4 + 1][row] = a0.y;
        As[q * 4 + 2][row] = a0.z; As[q * 4 + 3][row] = a0.w;
        As[q * 4 + 0][row + 32] = a1.x; As[q * 4 + 1][row + 32] = a1.y;
        As[q * 4 + 2][row + 32] = a1.z; As[q * 4 + 3][row + 32] = a1.w;
        Bs[q * 4 + 0][row] = b0.x; Bs[q * 4 + 1][row] = b0.y;
        Bs[q * 4 + 2][row] = b0.z; Bs[q * 4 + 3][row] = b0.w;
        Bs[q * 4 + 0][row + 32] = b1v.x; Bs[q * 4 + 1][row + 32] = b1v.y;
        Bs[q * 4 + 2][row + 32] = b1v.z; Bs[q * 4 + 3][row + 32] = b1v.w;
        __syncthreads();
        #pragma unroll
        for (int k = 0; k < 32; k++) {
            float av[4], bv[4];
            *(float4*)av = *(const float4*)&As[k][tm];
            *(float4*)bv = *(const float4*)&Bs[k][tn];
            #pragma unroll
            for (int i = 0; i < 4; i++)
                #pragma unroll
                for (int j = 0; j < 4; j++)
                    acc[i][j] = fmaf(av[i], bv[j], acc[i][j]);
        }
    }
    float4 bb = *(const float4*)&bias[j0 + tn];
    #pragma unroll
    for (int i = 0; i < 4; i++) {
        float4 o;
        o.x = acc[i][0] + bb.x; o.y = acc[i][1] + bb.y;
        o.z = acc[i][2] + bb.z; o.w = acc[i][3] + bb.w;
        *(float4*)&Y[(m0 + tm + i) * NOUT + j0 + tn] = o;
    }
}

// ---------------- per-column sum / sumsq over 16384 rows ----------------
template <int C>
__global__ __launch_bounds__(256) void stats_kernel(const float* __restrict__ Y,
                                                    float* __restrict__ sums,
                                                    float* __restrict__ sumsq) {
    int t = threadIdx.x;
    int col = t % C, sub = t / C;
    const int nsub = 256 / C;
    int r0 = blockIdx.x * 256;
    float s = 0.f, s2 = 0.f;
    for (int r = r0 + sub; r < r0 + 256; r += nsub) {
        float v = Y[r * C + col];
        s += v; s2 += v * v;
    }
    atomicAdd(&sums[col], s);
    atomicAdd(&sumsq[col], s2);
}

__global__ void finalize_kernel(const float* __restrict__ sums, const float* __restrict__ sumsq,
                                const float* __restrict__ g, const float* __restrict__ be,
                                float* __restrict__ scale, float* __restrict__ shift, int C) {
    int t = threadIdx.x;
    if (t < C) {
        float mean = sums[t] * (1.0f / N_FINE);
        float var = sumsq[t] * (1.0f / N_FINE) - mean * mean;
        float sc = g[t] * rsqrtf(var + EPS_BN);
        scale[t] = sc;
        shift[t] = be[t] - mean * sc;
    }
}

// ---------------- BN2+ReLU fused transposed store: out[c][n] ----------------
__global__ __launch_bounds__(256) void out_kernel(const float* __restrict__ Y2,
                                                  const float* __restrict__ scale2,
                                                  const float* __restrict__ shift2,
                                                  float* __restrict__ out) {
    __shared__ float tile[64][65];
    int t = threadIdx.x;
    int n0 = blockIdx.x * 64, c0 = blockIdx.y * 64;
    int cl = t & 63, rg = t >> 6;
    #pragma unroll
    for (int i = 0; i < 16; i++) {
        int r = rg + i * 4;
        tile[r][cl] = Y2[(n0 + r) * C2 + c0 + cl];
    }
    __syncthreads();
    #pragma unroll
    for (int i = 0; i < 16; i++) {
        int c = rg + i * 4;
        float v = fmaf(tile[cl][c], scale2[c0 + c], shift2[c0 + c]);
        out[(c0 + c) * N_FINE + n0 + cl] = fmaxf(v, 0.f);
    }
}

extern "C" void kernel_launch(void* const* d_in, const int* in_sizes, int n_in,
                              void* d_out, int out_size, void* d_ws, size_t ws_size,
                              hipStream_t stream) {
    const float* fine_xyz   = (const float*)d_in[0];
    const float* coarse_xyz = (const float*)d_in[1];
    const int*   fine_pid   = (const int*)d_in[2];
    const int*   coarse_pid = (const int*)d_in[3];
    const float* fine_feat  = (const float*)d_in[4];
    const float* coarse_feat= (const float*)d_in[5];
    const float* W1  = (const float*)d_in[6];
    const float* b1  = (const float*)d_in[7];
    const float* g1  = (const float*)d_in[8];
    const float* be1 = (const float*)d_in[9];
    const float* W2  = (const float*)d_in[10];
    const float* b2  = (const float*)d_in[11];
    const float* g2  = (const float*)d_in[12];
    const float* be2 = (const float*)d_in[13];
    float* out = (float*)d_out;

    char* ws = (char*)d_ws;
    int*    ranges = (int*)(ws + OFF_RANGES);
    float*  sums1  = (float*)(ws + OFF_SUMS);
    float*  sumsq1 = sums1 + 256;
    float*  sums2  = sums1 + 512;
    float*  sumsq2 = sums1 + 640;
    float*  scale1 = (float*)(ws + OFF_SCALE1);
    float*  shift1 = (float*)(ws + OFF_SHIFT1);
    float*  scale2 = (float*)(ws + OFF_SCALE2);
    float*  shift2 = (float*)(ws + OFF_SHIFT2);
    float4* cpack  = (float4*)(ws + OFF_CPACK);
    float*  cfT    = (float*)(ws + OFF_CFT);
    int*    idx3   = (int*)(ws + OFF_IDX3);
    float*  w3     = (float*)(ws + OFF_W3);
    float*  X      = (float*)(ws + OFF_XCAT);
    float*  Y1     = (float*)(ws + OFF_Y1);
    float*  Y2     = (float*)(ws + OFF_Y2);

    hipMemsetAsync(ws + OFF_SUMS, 0, 768 * sizeof(float), stream);

    range_kernel<<<1, 256, 0, stream>>>(coarse_pid, ranges);
    pack_coarse_kernel<<<S_COARSE / 256, 256, 0, stream>>>(coarse_xyz, cpack);
    transpose_cf_kernel<<<dim3(S_COARSE / 32, DC / 32), 256, 0, stream>>>(coarse_feat, cfT);
    knn_kernel<<<N_FINE / 16, 256, 0, stream>>>(fine_xyz, fine_pid, cpack, ranges, idx3, w3);
    build_x_kernel<<<N_FINE, 256, 0, stream>>>(idx3, w3, cfT, fine_feat, X);

    gemm_kernel<K1, C1, false><<<dim3(N_FINE / 64, C1 / 64), 256, 0, stream>>>(
        X, W1, b1, nullptr, nullptr, Y1);
    stats_kernel<C1><<<64, 256, 0, stream>>>(Y1, sums1, sumsq1);
    finalize_kernel<<<1, 256, 0, stream>>>(sums1, sumsq1, g1, be1, scale1, shift1, C1);

    gemm_kernel<C1, C2, true><<<dim3(N_FINE / 64, C2 / 64), 256, 0, stream>>>(
        Y1, W2, b2, scale1, shift1, Y2);
    stats_kernel<C2><<<64, 256, 0, stream>>>(Y2, sums2, sumsq2);
    finalize_kernel<<<1, 256, 0, stream>>>(sums2, sumsq2, g2, be2, scale2, shift2, C2);

    out_kernel<<<dim3(N_FINE / 64, C2 / 64), 256, 0, stream>>>(Y2, scale2, shift2, out);
}

// Round 2
// 286.827 us; speedup vs baseline: 1.1267x; 1.1267x over previous
//
#include <hip/hip_runtime.h>
#include <hip/hip_bf16.h>

#define N_FINE   16384
#define S_COARSE 4096
#define DC       256
#define DF       64
#define K1       320   // DC + DF
#define C1       256
#define C2       128
#define BIGF     1e8f
#define EPS_W    1e-8f
#define EPS_BN   1e-5f

// ---------------- workspace layout (bytes) ----------------
#define OFF_RANGES 0          // 8 ints: start[4], end[4]
#define OFF_SUMS   256        // sums1[256] sumsq1[256] sums2[128] sumsq2[128] = 768 f
#define OFF_SCALE1 3328       // 256 f
#define OFF_SHIFT1 4352       // 256 f
#define OFF_SCALE2 5376       // 128 f
#define OFF_SHIFT2 5888       // 128 f
#define OFF_CPACK  8192       // 4096 * float4 = 64 KiB
#define OFF_CFT    73728      // 4096*256*4 = 4 MiB
#define OFF_IDX3   4268032    // 16384*3 int
#define OFF_W3     4464640    // 16384*3 f
#define OFF_XCAT   4661248    // 16384*320*4 = 20 MiB
#define OFF_Y1     25632768   // 16384*256*4 = 16 MiB
#define OFF_Y2     42409984   // 16384*128*4 = 8 MiB

// ---------------- piece ranges ----------------
__global__ __launch_bounds__(256) void range_kernel(const int* __restrict__ cid,
                                                    int* __restrict__ ranges) {
    int t = threadIdx.x;
    if (t < 8) ranges[t] = 0;
    __syncthreads();
    for (int s = t; s < S_COARSE; s += 256) {
        int c = cid[s];
        if (s == 0 || cid[s - 1] != c) ranges[c] = s;          // start
        if (s == S_COARSE - 1 || cid[s + 1] != c) ranges[4 + c] = s + 1; // end
    }
}

// ---------------- pack coarse xyz + |c|^2 ----------------
__global__ __launch_bounds__(256) void pack_coarse_kernel(const float* __restrict__ cxyz,
                                                          float4* __restrict__ cpack) {
    int s = blockIdx.x * 256 + threadIdx.x;
    float x = cxyz[s], y = cxyz[S_COARSE + s], z = cxyz[2 * S_COARSE + s];
    cpack[s] = make_float4(x, y, z, x * x + y * y + z * z);
}

// ---------------- transpose coarse features [256][4096] -> [4096][256] ----------------
__global__ __launch_bounds__(256) void transpose_cf_kernel(const float* __restrict__ cf,
                                                           float* __restrict__ cfT) {
    __shared__ float tile[32][33];
    int tx = threadIdx.x & 31, ty = threadIdx.x >> 5;  // ty 0..7
    int s0 = blockIdx.x * 32, c0 = blockIdx.y * 32;
    #pragma unroll
    for (int i = 0; i < 4; i++) {
        int c = c0 + ty + i * 8;
        tile[ty + i * 8][tx] = cf[c * S_COARSE + s0 + tx];
    }
    __syncthreads();
    #pragma unroll
    for (int i = 0; i < 4; i++) {
        int s = ty + i * 8;
        cfT[(s0 + s) * DC + c0 + tx] = tile[tx][s];
    }
}

// ---------------- 3-NN within piece range + IDW weights ----------------
__global__ __launch_bounds__(256) void knn_kernel(const float* __restrict__ fxyz,
                                                  const int* __restrict__ fpid,
                                                  const float4* __restrict__ cpack,
                                                  const int* __restrict__ ranges,
                                                  int* __restrict__ idx3,
                                                  float* __restrict__ w3) {
    __shared__ float md[16][16][3];
    __shared__ int   mi[16][16][3];
    int t = threadIdx.x;
    int p = t & 15, ch = t >> 4;
    int n = blockIdx.x * 16 + p;
    int fid = fpid[n];
    float fx = fxyz[n], fy = fxyz[N_FINE + n], fz = fxyz[2 * N_FINE + n];
    float fn2 = fx * fx + fy * fy + fz * fz;
    int st = ranges[fid], en = ranges[4 + fid];
    int cnt = en - st;
    int L = (cnt + 15) >> 4;
    int cs = st + ch * L;
    int ce = min(cs + L, en);
    float d0 = BIGF, d1 = BIGF, d2v = BIGF;
    int i0 = -1, i1 = -1, i2 = -1;
    for (int s = cs; s < ce; ++s) {
        float4 c = cpack[s];
        float d = fn2 + c.w - 2.0f * (fx * c.x + fy * c.y + fz * c.z);
        if (d < d0)       { d2v = d1; i2 = i1; d1 = d0; i1 = i0; d0 = d; i0 = s; }
        else if (d < d1)  { d2v = d1; i2 = i1; d1 = d;  i1 = s; }
        else if (d < d2v) { d2v = d;  i2 = s; }
    }
    md[p][ch][0] = d0;  md[p][ch][1] = d1;  md[p][ch][2] = d2v;
    mi[p][ch][0] = i0;  mi[p][ch][1] = i1;  mi[p][ch][2] = i2;
    __syncthreads();
    if (t < 16) {
        d0 = d1 = d2v = BIGF; i0 = i1 = i2 = -1;
        for (int c = 0; c < 16; c++) {
            #pragma unroll
            for (int k = 0; k < 3; k++) {
                int ii = mi[t][c][k];
                if (ii < 0) continue;
                float d = md[t][c][k];
                if (d < d0)       { d2v = d1; i2 = i1; d1 = d0; i1 = i0; d0 = d; i0 = ii; }
                else if (d < d1)  { d2v = d1; i2 = i1; d1 = d;  i1 = ii; }
                else if (d < d2v) { d2v = d;  i2 = ii; }
            }
        }
        int cand = 0;
        while (i0 < 0 || i1 < 0 || i2 < 0) {
            if (cand >= st && cand < en) { cand = en; continue; }
            if (i0 < 0)      { i0 = cand; d0 = BIGF; }
            else if (i1 < 0) { i1 = cand; d1 = BIGF; }
            else             { i2 = cand; d2v = BIGF; }
            cand++;
        }
        float w0 = 1.0f / (d0 + EPS_W);
        float w1 = 1.0f / (d1 + EPS_W);
        float w2 = 1.0f / (d2v + EPS_W);
        float inv = 1.0f / (w0 + w1 + w2);
        idx3[n * 3 + 0] = i0; idx3[n * 3 + 1] = i1; idx3[n * 3 + 2] = i2;
        w3[n * 3 + 0] = w0 * inv; w3[n * 3 + 1] = w1 * inv; w3[n * 3 + 2] = w2 * inv;
    }
}

// ---------------- build x = [interp(256) | fine_feat(64)] row-major [N][320] ----------------
__global__ __launch_bounds__(256) void build_x_kernel(const int* __restrict__ idx3,
                                                      const float* __restrict__ w3,
                                                      const float* __restrict__ cfT,
                                                      const float* __restrict__ ff,
                                                      float* __restrict__ X) {
    int n = blockIdx.x, t = threadIdx.x;
    int i0 = idx3[n * 3], i1 = idx3[n * 3 + 1], i2 = idx3[n * 3 + 2];
    float w0 = w3[n * 3], w1 = w3[n * 3 + 1], w2 = w3[n * 3 + 2];
    float v = w0 * cfT[i0 * DC + t] + w1 * cfT[i1 * DC + t] + w2 * cfT[i2 * DC + t];
    X[n * K1 + t] = v;
    if (t < DF) X[n * K1 + DC + t] = ff[t * N_FINE + n];
}

// ---------------- tiled f32 GEMM with fused column stats (sum / sumsq) ----------------
// BM=BN=64, BK=32, 256 threads, 4x4 micro-tile. Optional fused BN+ReLU on A load.
// Epilogue: adds bias, stores Y, and shuffle-reduces per-column sum/sumsq over the
// 16 consecutive lanes sharing a column group, then atomicAdd (fuses old stats_kernel).
template <int KDIM, int NOUT, bool BN_IN>
__global__ __launch_bounds__(256) void gemm_kernel(const float* __restrict__ A,
                                                   const float* __restrict__ W,
                                                   const float* __restrict__ bias,
                                                   const float* __restrict__ scale,
                                                   const float* __restrict__ shift,
                                                   float* __restrict__ Y,
                                                   float* __restrict__ sums,
                                                   float* __restrict__ sumsq) {
    __shared__ float As[32][64];
    __shared__ float Bs[32][64];
    int t = threadIdx.x;
    int m0 = blockIdx.x * 64, j0 = blockIdx.y * 64;
    int row = t >> 3, q = t & 7;          // staging: row 0..31, q 0..7 (float4 along K)
    int tm = (t & 15) * 4, tn = (t >> 4) * 4;
    float acc[4][4] = {};
    for (int kt = 0; kt < KDIM; kt += 32) {
        float4 a0 = *(const float4*)&A[(m0 + row) * KDIM + kt + q * 4];
        float4 a1 = *(const float4*)&A[(m0 + row + 32) * KDIM + kt + q * 4];
        float4 b0 = *(const float4*)&W[(j0 + row) * KDIM + kt + q * 4];
        float4 b1v = *(const float4*)&W[(j0 + row + 32) * KDIM + kt + q * 4];
        if (BN_IN) {
            float4 s4 = *(const float4*)&scale[kt + q * 4];
            float4 h4 = *(const float4*)&shift[kt + q * 4];
            a0.x = fmaxf(fmaf(a0.x, s4.x, h4.x), 0.f);
            a0.y = fmaxf(fmaf(a0.y, s4.y, h4.y), 0.f);
            a0.z = fmaxf(fmaf(a0.z, s4.z, h4.z), 0.f);
            a0.w = fmaxf(fmaf(a0.w, s4.w, h4.w), 0.f);
            a1.x = fmaxf(fmaf(a1.x, s4.x, h4.x), 0.f);
            a1.y = fmaxf(fmaf(a1.y, s4.y, h4.y), 0.f);
            a1.z = fmaxf(fmaf(a1.z, s4.z, h4.z), 0.f);
            a1.w = fmaxf(fmaf(a1.w, s4.w, h4.w), 0.f);
        }
        __syncthreads();   // previous iteration's reads done before overwrite
        As[q * 4 + 0][row] = a0.x; As[q * 4 + 1][row] = a0.y;
        As[q * 4 + 2][row] = a0.z; As[q * 4 + 3][row] = a0.w;
        As[q * 4 + 0][row + 32] = a1.x; As[q * 4 + 1][row + 32] = a1.y;
        As[q * 4 + 2][row + 32] = a1.z; As[q * 4 + 3][row + 32] = a1.w;
        Bs[q * 4 + 0][row] = b0.x; Bs[q * 4 + 1][row] = b0.y;
        Bs[q * 4 + 2][row] = b0.z; Bs[q * 4 + 3][row] = b0.w;
        Bs[q * 4 + 0][row + 32] = b1v.x; Bs[q * 4 + 1][row + 32] = b1v.y;
        Bs[q * 4 + 2][row + 32] = b1v.z; Bs[q * 4 + 3][row + 32] = b1v.w;
        __syncthreads();
        #pragma unroll
        for (int k = 0; k < 32; k++) {
            float av[4], bv[4];
            *(float4*)av = *(const float4*)&As[k][tm];
            *(float4*)bv = *(const float4*)&Bs[k][tn];
            #pragma unroll
            for (int i = 0; i < 4; i++)
                #pragma unroll
                for (int j = 0; j < 4; j++)
                    acc[i][j] = fmaf(av[i], bv[j], acc[i][j]);
        }
    }
    float4 bb = *(const float4*)&bias[j0 + tn];
    float s[4] = {0.f, 0.f, 0.f, 0.f};
    float s2[4] = {0.f, 0.f, 0.f, 0.f};
    #pragma unroll
    for (int i = 0; i < 4; i++) {
        float4 o;
        o.x = acc[i][0] + bb.x; o.y = acc[i][1] + bb.y;
        o.z = acc[i][2] + bb.z; o.w = acc[i][3] + bb.w;
        *(float4*)&Y[(m0 + tm + i) * NOUT + j0 + tn] = o;
        s[0] += o.x; s2[0] += o.x * o.x;
        s[1] += o.y; s2[1] += o.y * o.y;
        s[2] += o.z; s2[2] += o.z * o.z;
        s[3] += o.w; s2[3] += o.w * o.w;
    }
    // reduce over the 16 consecutive lanes that share this tn (same wave)
    #pragma unroll
    for (int m = 1; m < 16; m <<= 1) {
        #pragma unroll
        for (int j = 0; j < 4; j++) {
            s[j]  += __shfl_xor(s[j],  m, 64);
            s2[j] += __shfl_xor(s2[j], m, 64);
        }
    }
    if ((t & 15) == 0) {
        #pragma unroll
        for (int j = 0; j < 4; j++) {
            atomicAdd(&sums[j0 + tn + j],  s[j]);
            atomicAdd(&sumsq[j0 + tn + j], s2[j]);
        }
    }
}

__global__ void finalize_kernel(const float* __restrict__ sums, const float* __restrict__ sumsq,
                                const float* __restrict__ g, const float* __restrict__ be,
                                float* __restrict__ scale, float* __restrict__ shift, int C) {
    int t = threadIdx.x;
    if (t < C) {
        float mean = sums[t] * (1.0f / N_FINE);
        float var = sumsq[t] * (1.0f / N_FINE) - mean * mean;
        float sc = g[t] * rsqrtf(var + EPS_BN);
        scale[t] = sc;
        shift[t] = be[t] - mean * sc;
    }
}

// ---------------- BN2+ReLU fused transposed store: out[c][n] ----------------
__global__ __launch_bounds__(256) void out_kernel(const float* __restrict__ Y2,
                                                  const float* __restrict__ scale2,
                                                  const float* __restrict__ shift2,
                                                  float* __restrict__ out) {
    __shared__ float tile[64][65];
    int t = threadIdx.x;
    int n0 = blockIdx.x * 64, c0 = blockIdx.y * 64;
    int cl = t & 63, rg = t >> 6;
    #pragma unroll
    for (int i = 0; i < 16; i++) {
        int r = rg + i * 4;
        tile[r][cl] = Y2[(n0 + r) * C2 + c0 + cl];
    }
    __syncthreads();
    #pragma unroll
    for (int i = 0; i < 16; i++) {
        int c = rg + i * 4;
        float v = fmaf(tile[cl][c], scale2[c0 + c], shift2[c0 + c]);
        out[(c0 + c) * N_FINE + n0 + cl] = fmaxf(v, 0.f);
    }
}

extern "C" void kernel_launch(void* const* d_in, const int* in_sizes, int n_in,
                              void* d_out, int out_size, void* d_ws, size_t ws_size,
                              hipStream_t stream) {
    const float* fine_xyz   = (const float*)d_in[0];
    const float* coarse_xyz = (const float*)d_in[1];
    const int*   fine_pid   = (const int*)d_in[2];
    const int*   coarse_pid = (const int*)d_in[3];
    const float* fine_feat  = (const float*)d_in[4];
    const float* coarse_feat= (const float*)d_in[5];
    const float* W1  = (const float*)d_in[6];
    const float* b1  = (const float*)d_in[7];
    const float* g1  = (const float*)d_in[8];
    const float* be1 = (const float*)d_in[9];
    const float* W2  = (const float*)d_in[10];
    const float* b2  = (const float*)d_in[11];
    const float* g2  = (const float*)d_in[12];
    const float* be2 = (const float*)d_in[13];
    float* out = (float*)d_out;

    char* ws = (char*)d_ws;
    int*    ranges = (int*)(ws + OFF_RANGES);
    float*  sums1  = (float*)(ws + OFF_SUMS);
    float*  sumsq1 = sums1 + 256;
    float*  sums2  = sums1 + 512;
    float*  sumsq2 = sums1 + 640;
    float*  scale1 = (float*)(ws + OFF_SCALE1);
    float*  shift1 = (float*)(ws + OFF_SHIFT1);
    float*  scale2 = (float*)(ws + OFF_SCALE2);
    float*  shift2 = (float*)(ws + OFF_SHIFT2);
    float4* cpack  = (float4*)(ws + OFF_CPACK);
    float*  cfT    = (float*)(ws + OFF_CFT);
    int*    idx3   = (int*)(ws + OFF_IDX3);
    float*  w3     = (float*)(ws + OFF_W3);
    float*  X      = (float*)(ws + OFF_XCAT);
    float*  Y1     = (float*)(ws + OFF_Y1);
    float*  Y2     = (float*)(ws + OFF_Y2);

    hipMemsetAsync(ws + OFF_SUMS, 0, 768 * sizeof(float), stream);

    range_kernel<<<1, 256, 0, stream>>>(coarse_pid, ranges);
    pack_coarse_kernel<<<S_COARSE / 256, 256, 0, stream>>>(coarse_xyz, cpack);
    transpose_cf_kernel<<<dim3(S_COARSE / 32, DC / 32), 256, 0, stream>>>(coarse_feat, cfT);
    knn_kernel<<<N_FINE / 16, 256, 0, stream>>>(fine_xyz, fine_pid, cpack, ranges, idx3, w3);
    build_x_kernel<<<N_FINE, 256, 0, stream>>>(idx3, w3, cfT, fine_feat, X);

    gemm_kernel<K1, C1, false><<<dim3(N_FINE / 64, C1 / 64), 256, 0, stream>>>(
        X, W1, b1, nullptr, nullptr, Y1, sums1, sumsq1);
    finalize_kernel<<<1, 256, 0, stream>>>(sums1, sumsq1, g1, be1, scale1, shift1, C1);

    gemm_kernel<C1, C2, true><<<dim3(N_FINE / 64, C2 / 64), 256, 0, stream>>>(
        Y1, W2, b2, scale1, shift1, Y2, sums2, sumsq2);
    finalize_kernel<<<1, 256, 0, stream>>>(sums2, sumsq2, g2, be2, scale2, shift2, C2);

    out_kernel<<<dim3(N_FINE / 64, C2 / 64), 256, 0, stream>>>(Y2, scale2, shift2, out);
}

// Round 5
// 191.135 us; speedup vs baseline: 1.6908x; 1.5006x over previous
//
#include <hip/hip_runtime.h>
#include <hip/hip_bf16.h>

#define N_FINE   16384
#define S_COARSE 4096
#define DC       256
#define DF       64
#define K1       320   // DC + DF
#define C1       256
#define C2       128
#define BIGF     1e8f
#define EPS_W    1e-8f
#define EPS_BN   1e-5f

typedef __attribute__((ext_vector_type(8))) short bf16x8;
typedef __attribute__((ext_vector_type(8))) unsigned short u16x8;
typedef __attribute__((ext_vector_type(4))) float f32x4;

// ---------------- workspace layout (bytes) ----------------
#define OFF_RANGES 0          // 8 ints
#define OFF_SUMS   256        // sums1[256] sumsq1[256] sums2[128] sumsq2[128]
#define OFF_SCALE1 3328
#define OFF_SHIFT1 4352
#define OFF_SCALE2 5376
#define OFF_SHIFT2 5888
#define OFF_CPACK  8192       // 4096 * float4
#define OFF_CFT    73728      // 4096*256*4 = 4 MiB
#define OFF_IDX3   4268032    // 16384*3 int
#define OFF_W3     4464640    // 16384*3 f
#define OFF_W1B    4661248    // 256*320*2 = 160 KiB (bf16)
#define OFF_W2B    4825088    // 128*256*2 = 64 KiB (bf16)
#define OFF_X      4890624    // 16384*320*2 = 10 MiB (bf16)
#define OFF_Y1     15376384   // 16384*256*2 = 8 MiB (bf16)
#define OFF_Y2     23764992   // 16384*128*4 = 8 MiB (f32)

__device__ inline unsigned short f2bf_bits(float f) {
    __hip_bfloat16 h = __float2bfloat16(f);
    unsigned short u;
    __builtin_memcpy(&u, &h, 2);
    return u;
}

// ---------------- piece ranges ----------------
__global__ __launch_bounds__(256) void range_kernel(const int* __restrict__ cid,
                                                    int* __restrict__ ranges) {
    int t = threadIdx.x;
    if (t < 8) ranges[t] = 0;
    __syncthreads();
    for (int s = t; s < S_COARSE; s += 256) {
        int c = cid[s];
        if (s == 0 || cid[s - 1] != c) ranges[c] = s;
        if (s == S_COARSE - 1 || cid[s + 1] != c) ranges[4 + c] = s + 1;
    }
}

// ---------------- pack coarse xyz + |c|^2 ----------------
__global__ __launch_bounds__(256) void pack_coarse_kernel(const float* __restrict__ cxyz,
                                                          float4* __restrict__ cpack) {
    int s = blockIdx.x * 256 + threadIdx.x;
    float x = cxyz[s], y = cxyz[S_COARSE + s], z = cxyz[2 * S_COARSE + s];
    cpack[s] = make_float4(x, y, z, x * x + y * y + z * z);
}

// ---------------- transpose coarse features [256][4096] -> [4096][256] ----------------
__global__ __launch_bounds__(256) void transpose_cf_kernel(const float* __restrict__ cf,
                                                           float* __restrict__ cfT) {
    __shared__ float tile[32][33];
    int tx = threadIdx.x & 31, ty = threadIdx.x >> 5;
    int s0 = blockIdx.x * 32, c0 = blockIdx.y * 32;
    #pragma unroll
    for (int i = 0; i < 4; i++) {
        int c = c0 + ty + i * 8;
        tile[ty + i * 8][tx] = cf[c * S_COARSE + s0 + tx];
    }
    __syncthreads();
    #pragma unroll
    for (int i = 0; i < 4; i++) {
        int s = ty + i * 8;
        cfT[(s0 + s) * DC + c0 + tx] = tile[tx][s];
    }
}

// ---------------- convert W1 / W2 to bf16 ----------------
__global__ __launch_bounds__(256) void cvtw_kernel(const float* __restrict__ W1,
                                                   const float* __restrict__ W2,
                                                   unsigned short* __restrict__ W1b,
                                                   unsigned short* __restrict__ W2b) {
    int i = blockIdx.x * 256 + threadIdx.x;
    if (i < C1 * K1) W1b[i] = f2bf_bits(W1[i]);
    if (i < C2 * C1) W2b[i] = f2bf_bits(W2[i]);
}

// ---------------- 3-NN within piece range + IDW weights ----------------
__global__ __launch_bounds__(256) void knn_kernel(const float* __restrict__ fxyz,
                                                  const int* __restrict__ fpid,
                                                  const float4* __restrict__ cpack,
                                                  const int* __restrict__ ranges,
                                                  int* __restrict__ idx3,
                                                  float* __restrict__ w3) {
    __shared__ float md[16][16][3];
    __shared__ int   mi[16][16][3];
    int t = threadIdx.x;
    int p = t & 15, ch = t >> 4;
    int n = blockIdx.x * 16 + p;
    int fid = fpid[n];
    float fx = fxyz[n], fy = fxyz[N_FINE + n], fz = fxyz[2 * N_FINE + n];
    float fn2 = fx * fx + fy * fy + fz * fz;
    int st = ranges[fid], en = ranges[4 + fid];
    int cnt = en - st;
    int L = (cnt + 15) >> 4;
    int cs = st + ch * L;
    int ce = min(cs + L, en);
    float d0 = BIGF, d1 = BIGF, d2v = BIGF;
    int i0 = -1, i1 = -1, i2 = -1;
    for (int s = cs; s < ce; ++s) {
        float4 c = cpack[s];
        float d = fn2 + c.w - 2.0f * (fx * c.x + fy * c.y + fz * c.z);
        if (d < d0)       { d2v = d1; i2 = i1; d1 = d0; i1 = i0; d0 = d; i0 = s; }
        else if (d < d1)  { d2v = d1; i2 = i1; d1 = d;  i1 = s; }
        else if (d < d2v) { d2v = d;  i2 = s; }
    }
    md[p][ch][0] = d0;  md[p][ch][1] = d1;  md[p][ch][2] = d2v;
    mi[p][ch][0] = i0;  mi[p][ch][1] = i1;  mi[p][ch][2] = i2;
    __syncthreads();
    if (t < 16) {
        d0 = d1 = d2v = BIGF; i0 = i1 = i2 = -1;
        for (int c = 0; c < 16; c++) {
            #pragma unroll
            for (int k = 0; k < 3; k++) {
                int ii = mi[t][c][k];
                if (ii < 0) continue;
                float d = md[t][c][k];
                if (d < d0)       { d2v = d1; i2 = i1; d1 = d0; i1 = i0; d0 = d; i0 = ii; }
                else if (d < d1)  { d2v = d1; i2 = i1; d1 = d;  i1 = ii; }
                else if (d < d2v) { d2v = d;  i2 = ii; }
            }
        }
        int cand = 0;
        while (i0 < 0 || i1 < 0 || i2 < 0) {
            if (cand >= st && cand < en) { cand = en; continue; }
            if (i0 < 0)      { i0 = cand; d0 = BIGF; }
            else if (i1 < 0) { i1 = cand; d1 = BIGF; }
            else             { i2 = cand; d2v = BIGF; }
            cand++;
        }
        float w0 = 1.0f / (d0 + EPS_W);
        float w1 = 1.0f / (d1 + EPS_W);
        float w2 = 1.0f / (d2v + EPS_W);
        float inv = 1.0f / (w0 + w1 + w2);
        idx3[n * 3 + 0] = i0; idx3[n * 3 + 1] = i1; idx3[n * 3 + 2] = i2;
        w3[n * 3 + 0] = w0 * inv; w3[n * 3 + 1] = w1 * inv; w3[n * 3 + 2] = w2 * inv;
    }
}

// ---------------- build x = [interp(256) | fine_feat(64)] row-major [N][320] bf16 ----------------
__global__ __launch_bounds__(256) void build_x_kernel(const int* __restrict__ idx3,
                                                      const float* __restrict__ w3,
                                                      const float* __restrict__ cfT,
                                                      const float* __restrict__ ff,
                                                      unsigned short* __restrict__ X) {
    int n = blockIdx.x, t = threadIdx.x;
    int i0 = idx3[n * 3], i1 = idx3[n * 3 + 1], i2 = idx3[n * 3 + 2];
    float w0 = w3[n * 3], w1 = w3[n * 3 + 1], w2 = w3[n * 3 + 2];
    float v = w0 * cfT[i0 * DC + t] + w1 * cfT[i1 * DC + t] + w2 * cfT[i2 * DC + t];
    X[n * K1 + t] = f2bf_bits(v);
    if (t < DF) X[n * K1 + DC + t] = f2bf_bits(ff[t * N_FINE + n]);
}

// ---------------- bf16 MFMA GEMM: Y[m][n] = dot(A[m][:K], B[n][:K]) + bias[n] ----------------
// BM=128, BN=64, 256 threads = 4 waves (2M x 2N), wave tile 64x32 = 4x2 16x16 frags.
// LDS granule layout [kslot][row^(4*kslot)][8 bf16] -> coalesced global loads AND
// <=2-way (free) bank access on both ds_write_b128 and ds_read_b128.
// Optional BN+ReLU transform on A load (GEMM2). Epilogue: bias add, store
// (bf16 or f32), fused per-column sum/sumsq shuffle-reduce + atomicAdd.
template <int KDIM, int NOUT, bool BN_IN, bool OUT_BF16>
__global__ __launch_bounds__(256) void mfma_gemm_kernel(
    const unsigned short* __restrict__ A,   // [M][KDIM] bf16 bits
    const unsigned short* __restrict__ B,   // [NOUT][KDIM] bf16 bits
    const float* __restrict__ bias,
    const float* __restrict__ scale,
    const float* __restrict__ shift,
    void* __restrict__ Yout,
    float* __restrict__ sums, float* __restrict__ sumsq)
{
    __shared__ __align__(16) unsigned short As[4 * 128 * 8];  // 8 KiB
    __shared__ __align__(16) unsigned short Bs[4 * 64 * 8];   // 4 KiB
    int t = threadIdx.x;
    int m0 = blockIdx.x * 128, j0 = blockIdx.y * 64;
    int lane = t & 63, wid = t >> 6;
    int wm = (wid >> 1) * 64, wn = (wid & 1) * 32;

    // staging: memory-order granules, ks = t&3 (64B contiguous per row across 4 lanes)
    int ksA = t & 3;
    int rowA0 = t >> 2;            // 0..63
    int rowA1 = 64 + rowA0;        // 64..127
    int fxw = ksA << 2;
    int gA0 = ksA * 128 + (rowA0 ^ fxw);
    int gA1 = ksA * 128 + (rowA1 ^ fxw);
    int gB  = ksA * 64 + (rowA0 ^ fxw);
    const unsigned short* pa0 = A + (size_t)(m0 + rowA0) * KDIM + ksA * 8;
    const unsigned short* pa1 = A + (size_t)(m0 + rowA1) * KDIM + ksA * 8;
    const unsigned short* pb  = B + (size_t)(j0 + rowA0) * KDIM + ksA * 8;

    f32x4 acc[4][2] = {};
    int ks = lane >> 4, r16 = lane & 15;
    int fxr = ks << 2;

    for (int kt = 0; kt < KDIM; kt += 32) {
        u16x8 va0 = *(const u16x8*)(pa0 + kt);
        u16x8 va1 = *(const u16x8*)(pa1 + kt);
        u16x8 vb  = *(const u16x8*)(pb + kt);
        if (BN_IN) {
            int kb = kt + ksA * 8;
            #pragma unroll
            for (int i = 0; i < 8; i++) {
                float sc = scale[kb + i], sh = shift[kb + i];
                float f0 = __uint_as_float(((unsigned)va0[i]) << 16);
                float f1 = __uint_as_float(((unsigned)va1[i]) << 16);
                va0[i] = f2bf_bits(fmaxf(fmaf(f0, sc, sh), 0.f));
                va1[i] = f2bf_bits(fmaxf(fmaf(f1, sc, sh), 0.f));
            }
        }
        __syncthreads();   // previous iteration's frag reads complete
        *(u16x8*)&As[gA0 * 8] = va0;
        *(u16x8*)&As[gA1 * 8] = va1;
        *(u16x8*)&Bs[gB * 8]  = vb;
        __syncthreads();
        bf16x8 af[4], bfr[2];
        #pragma unroll
        for (int mi = 0; mi < 4; mi++)
            af[mi] = *(const bf16x8*)&As[(ks * 128 + wm + mi * 16 + (r16 ^ fxr)) * 8];
        #pragma unroll
        for (int nj = 0; nj < 2; nj++)
            bfr[nj] = *(const bf16x8*)&Bs[(ks * 64 + wn + nj * 16 + (r16 ^ fxr)) * 8];
        #pragma unroll
        for (int mi = 0; mi < 4; mi++)
            #pragma unroll
            for (int nj = 0; nj < 2; nj++)
                acc[mi][nj] = __builtin_amdgcn_mfma_f32_16x16x32_bf16(af[mi], bfr[nj], acc[mi][nj], 0, 0, 0);
    }

    // epilogue: C/D layout col(n)=lane&15, row(m)=4*(lane>>4)+reg  [m89/m91]
    float sl[2] = {0.f, 0.f}, s2l[2] = {0.f, 0.f};
    #pragma unroll
    for (int nj = 0; nj < 2; nj++) {
        int n = j0 + wn + nj * 16 + r16;
        float bb = bias[n];
        #pragma unroll
        for (int mi = 0; mi < 4; mi++) {
            #pragma unroll
            for (int r = 0; r < 4; r++) {
                int m = m0 + wm + mi * 16 + ks * 4 + r;
                float o = acc[mi][nj][r] + bb;
                if (OUT_BF16) ((unsigned short*)Yout)[(size_t)m * NOUT + n] = f2bf_bits(o);
                else          ((float*)Yout)[(size_t)m * NOUT + n] = o;
                sl[nj] += o; s2l[nj] += o * o;
            }
        }
    }
    #pragma unroll
    for (int nj = 0; nj < 2; nj++) {
        sl[nj]  += __shfl_xor(sl[nj],  16, 64);
        sl[nj]  += __shfl_xor(sl[nj],  32, 64);
        s2l[nj] += __shfl_xor(s2l[nj], 16, 64);
        s2l[nj] += __shfl_xor(s2l[nj], 32, 64);
    }
    if (lane < 16) {
        atomicAdd(&sums[j0 + wn + lane],       sl[0]);
        atomicAdd(&sums[j0 + wn + 16 + lane],  sl[1]);
        atomicAdd(&sumsq[j0 + wn + lane],      s2l[0]);
        atomicAdd(&sumsq[j0 + wn + 16 + lane], s2l[1]);
    }
}

__global__ void finalize_kernel(const float* __restrict__ sums, const float* __restrict__ sumsq,
                                const float* __restrict__ g, const float* __restrict__ be,
                                float* __restrict__ scale, float* __restrict__ shift, int C) {
    int t = threadIdx.x;
    if (t < C) {
        float mean = sums[t] * (1.0f / N_FINE);
        float var = sumsq[t] * (1.0f / N_FINE) - mean * mean;
        float sc = g[t] * rsqrtf(var + EPS_BN);
        scale[t] = sc;
        shift[t] = be[t] - mean * sc;
    }
}

// ---------------- BN2+ReLU fused transposed store: out[c][n] ----------------
__global__ __launch_bounds__(256) void out_kernel(const float* __restrict__ Y2,
                                                  const float* __restrict__ scale2,
                                                  const float* __restrict__ shift2,
                                                  float* __restrict__ out) {
    __shared__ float tile[64][65];
    int t = threadIdx.x;
    int n0 = blockIdx.x * 64, c0 = blockIdx.y * 64;
    int cl = t & 63, rg = t >> 6;
    #pragma unroll
    for (int i = 0; i < 16; i++) {
        int r = rg + i * 4;
        tile[r][cl] = Y2[(n0 + r) * C2 + c0 + cl];
    }
    __syncthreads();
    #pragma unroll
    for (int i = 0; i < 16; i++) {
        int c = rg + i * 4;
        float v = fmaf(tile[cl][c], scale2[c0 + c], shift2[c0 + c]);
        out[(c0 + c) * N_FINE + n0 + cl] = fmaxf(v, 0.f);
    }
}

extern "C" void kernel_launch(void* const* d_in, const int* in_sizes, int n_in,
                              void* d_out, int out_size, void* d_ws, size_t ws_size,
                              hipStream_t stream) {
    const float* fine_xyz   = (const float*)d_in[0];
    const float* coarse_xyz = (const float*)d_in[1];
    const int*   fine_pid   = (const int*)d_in[2];
    const int*   coarse_pid = (const int*)d_in[3];
    const float* fine_feat  = (const float*)d_in[4];
    const float* coarse_feat= (const float*)d_in[5];
    const float* W1  = (const float*)d_in[6];
    const float* b1  = (const float*)d_in[7];
    const float* g1  = (const float*)d_in[8];
    const float* be1 = (const float*)d_in[9];
    const float* W2  = (const float*)d_in[10];
    const float* b2  = (const float*)d_in[11];
    const float* g2  = (const float*)d_in[12];
    const float* be2 = (const float*)d_in[13];
    float* out = (float*)d_out;

    char* ws = (char*)d_ws;
    int*    ranges = (int*)(ws + OFF_RANGES);
    float*  sums1  = (float*)(ws + OFF_SUMS);
    float*  sumsq1 = sums1 + 256;
    float*  sums2  = sums1 + 512;
    float*  sumsq2 = sums1 + 640;
    float*  scale1 = (float*)(ws + OFF_SCALE1);
    float*  shift1 = (float*)(ws + OFF_SHIFT1);
    float*  scale2 = (float*)(ws + OFF_SCALE2);
    float*  shift2 = (float*)(ws + OFF_SHIFT2);
    float4* cpack  = (float4*)(ws + OFF_CPACK);
    float*  cfT    = (float*)(ws + OFF_CFT);
    int*    idx3   = (int*)(ws + OFF_IDX3);
    float*  w3     = (float*)(ws + OFF_W3);
    unsigned short* W1b = (unsigned short*)(ws + OFF_W1B);
    unsigned short* W2b = (unsigned short*)(ws + OFF_W2B);
    unsigned short* X   = (unsigned short*)(ws + OFF_X);
    unsigned short* Y1  = (unsigned short*)(ws + OFF_Y1);
    float*          Y2  = (float*)(ws + OFF_Y2);

    hipMemsetAsync(ws + OFF_SUMS, 0, 768 * sizeof(float), stream);

    range_kernel<<<1, 256, 0, stream>>>(coarse_pid, ranges);
    pack_coarse_kernel<<<S_COARSE / 256, 256, 0, stream>>>(coarse_xyz, cpack);
    transpose_cf_kernel<<<dim3(S_COARSE / 32, DC / 32), 256, 0, stream>>>(coarse_feat, cfT);
    cvtw_kernel<<<(C1 * K1 + 255) / 256, 256, 0, stream>>>(W1, W2, W1b, W2b);
    knn_kernel<<<N_FINE / 16, 256, 0, stream>>>(fine_xyz, fine_pid, cpack, ranges, idx3, w3);
    build_x_kernel<<<N_FINE, 256, 0, stream>>>(idx3, w3, cfT, fine_feat, X);

    mfma_gemm_kernel<K1, C1, false, true><<<dim3(N_FINE / 128, C1 / 64), 256, 0, stream>>>(
        X, W1b, b1, nullptr, nullptr, Y1, sums1, sumsq1);
    finalize_kernel<<<1, 256, 0, stream>>>(sums1, sumsq1, g1, be1, scale1, shift1, C1);

    mfma_gemm_kernel<C1, C2, true, false><<<dim3(N_FINE / 128, C2 / 64), 256, 0, stream>>>(
        Y1, W2b, b2, scale1, shift1, Y2, sums2, sumsq2);
    finalize_kernel<<<1, 256, 0, stream>>>(sums2, sumsq2, g2, be2, scale2, shift2, C2);

    out_kernel<<<dim3(N_FINE / 64, C2 / 64), 256, 0, stream>>>(Y2, scale2, shift2, out);
}

// Round 6
// 182.661 us; speedup vs baseline: 1.7692x; 1.0464x over previous
//
#include <hip/hip_runtime.h>
#include <hip/hip_bf16.h>

#define N_FINE   16384
#define S_COARSE 4096
#define DC       256
#define DF       64
#define K1       320   // DC + DF
#define C1       256
#define C2       128
#define BIGF     1e8f
#define EPS_W    1e-8f
#define EPS_BN   1e-5f

typedef __attribute__((ext_vector_type(8))) short bf16x8;
typedef __attribute__((ext_vector_type(8))) unsigned short u16x8;
typedef __attribute__((ext_vector_type(4))) float f32x4;

// ---------------- workspace layout (bytes) ----------------
#define OFF_RANGES 0          // 8 ints
#define OFF_SUMS   256        // sums1[256] sumsq1[256] sums2[128] sumsq2[128]
#define OFF_SCALE1 3328
#define OFF_SHIFT1 4352
#define OFF_SCALE2 5376
#define OFF_SHIFT2 5888
#define OFF_CPACK  8192       // 4096 * float4
#define OFF_CFT    73728      // 4096*256*4 = 4 MiB
#define OFF_IDX3   4268032    // 16384*3 int
#define OFF_W3     4464640    // 16384*3 f
#define OFF_W1B    4661248    // 256*320*2 = 160 KiB (bf16)
#define OFF_W2B    4825088    // 128*256*2 = 64 KiB (bf16)
#define OFF_Y1     4890624    // 16384*256*2 = 8 MiB (bf16)
#define OFF_Y2     13279232   // 16384*128*4 = 8 MiB (f32)

__device__ inline unsigned short f2bf_bits(float f) {
    __hip_bfloat16 h = __float2bfloat16(f);
    unsigned short u;
    __builtin_memcpy(&u, &h, 2);
    return u;
}

// ---------------- fused setup: range | zero sums | pack | cvtw | transpose ----------------
// blocks: 0 = range+zero, 1..16 = pack, 17..336 = cvtw, 337..1360 = transpose_cf
__global__ __launch_bounds__(256) void setup_kernel(
    const int* __restrict__ cid, int* __restrict__ ranges, float* __restrict__ sums,
    const float* __restrict__ cxyz, float4* __restrict__ cpack,
    const float* __restrict__ W1, const float* __restrict__ W2,
    unsigned short* __restrict__ W1b, unsigned short* __restrict__ W2b,
    const float* __restrict__ cf, float* __restrict__ cfT)
{
    __shared__ float tile[32][33];
    int b = blockIdx.x, t = threadIdx.x;
    if (b == 0) {
        if (t < 8) ranges[t] = 0;
        for (int i = t; i < 768; i += 256) sums[i] = 0.f;
        __syncthreads();
        for (int s = t; s < S_COARSE; s += 256) {
            int c = cid[s];
            if (s == 0 || cid[s - 1] != c) ranges[c] = s;
            if (s == S_COARSE - 1 || cid[s + 1] != c) ranges[4 + c] = s + 1;
        }
    } else if (b <= 16) {
        int s = (b - 1) * 256 + t;
        float x = cxyz[s], y = cxyz[S_COARSE + s], z = cxyz[2 * S_COARSE + s];
        cpack[s] = make_float4(x, y, z, x * x + y * y + z * z);
    } else if (b <= 336) {
        int i = (b - 17) * 256 + t;     // covers 81920 = C1*K1; C2*C1=32768 subset
        W1b[i] = f2bf_bits(W1[i]);
        if (i < C2 * C1) W2b[i] = f2bf_bits(W2[i]);
    } else {
        int lb = b - 337;                // 1024 transpose blocks
        int tx = t & 31, ty = t >> 5;
        int s0 = (lb & 127) * 32, c0 = (lb >> 7) * 32;
        #pragma unroll
        for (int i = 0; i < 4; i++)
            tile[ty + i * 8][tx] = cf[(c0 + ty + i * 8) * S_COARSE + s0 + tx];
        __syncthreads();
        #pragma unroll
        for (int i = 0; i < 4; i++) {
            int s = ty + i * 8;
            cfT[(s0 + s) * DC + c0 + tx] = tile[tx][s];
        }
    }
}

// ---------------- 3-NN within piece range + IDW weights ----------------
__global__ __launch_bounds__(256) void knn_kernel(const float* __restrict__ fxyz,
                                                  const int* __restrict__ fpid,
                                                  const float4* __restrict__ cpack,
                                                  const int* __restrict__ ranges,
                                                  int* __restrict__ idx3,
                                                  float* __restrict__ w3) {
    __shared__ float md[16][16][3];
    __shared__ int   mi[16][16][3];
    int t = threadIdx.x;
    int p = t & 15, ch = t >> 4;
    int n = blockIdx.x * 16 + p;
    int fid = fpid[n];
    float fx = fxyz[n], fy = fxyz[N_FINE + n], fz = fxyz[2 * N_FINE + n];
    float fn2 = fx * fx + fy * fy + fz * fz;
    int st = ranges[fid], en = ranges[4 + fid];
    int cnt = en - st;
    int L = (cnt + 15) >> 4;
    int cs = st + ch * L;
    int ce = min(cs + L, en);
    float d0 = BIGF, d1 = BIGF, d2v = BIGF;
    int i0 = -1, i1 = -1, i2 = -1;
    for (int s = cs; s < ce; ++s) {
        float4 c = cpack[s];
        float d = fn2 + c.w - 2.0f * (fx * c.x + fy * c.y + fz * c.z);
        if (d < d0)       { d2v = d1; i2 = i1; d1 = d0; i1 = i0; d0 = d; i0 = s; }
        else if (d < d1)  { d2v = d1; i2 = i1; d1 = d;  i1 = s; }
        else if (d < d2v) { d2v = d;  i2 = s; }
    }
    md[p][ch][0] = d0;  md[p][ch][1] = d1;  md[p][ch][2] = d2v;
    mi[p][ch][0] = i0;  mi[p][ch][1] = i1;  mi[p][ch][2] = i2;
    __syncthreads();
    if (t < 16) {
        d0 = d1 = d2v = BIGF; i0 = i1 = i2 = -1;
        for (int c = 0; c < 16; c++) {
            #pragma unroll
            for (int k = 0; k < 3; k++) {
                int ii = mi[t][c][k];
                if (ii < 0) continue;
                float d = md[t][c][k];
                if (d < d0)       { d2v = d1; i2 = i1; d1 = d0; i1 = i0; d0 = d; i0 = ii; }
                else if (d < d1)  { d2v = d1; i2 = i1; d1 = d;  i1 = ii; }
                else if (d < d2v) { d2v = d;  i2 = ii; }
            }
        }
        int cand = 0;
        while (i0 < 0 || i1 < 0 || i2 < 0) {
            if (cand >= st && cand < en) { cand = en; continue; }
            if (i0 < 0)      { i0 = cand; d0 = BIGF; }
            else if (i1 < 0) { i1 = cand; d1 = BIGF; }
            else             { i2 = cand; d2v = BIGF; }
            cand++;
        }
        float w0 = 1.0f / (d0 + EPS_W);
        float w1 = 1.0f / (d1 + EPS_W);
        float w2 = 1.0f / (d2v + EPS_W);
        float inv = 1.0f / (w0 + w1 + w2);
        idx3[n * 3 + 0] = i0; idx3[n * 3 + 1] = i1; idx3[n * 3 + 2] = i2;
        w3[n * 3 + 0] = w0 * inv; w3[n * 3 + 1] = w1 * inv; w3[n * 3 + 2] = w2 * inv;
    }
}

// ---------------- fused interp + GEMM1 + stats ----------------
// BM=32, BN=256 (full output width, interp computed once), grid (512,1), 4 waves.
// A-tile gathered from cfT (f32, L2-resident) with IDW weights, converted to bf16 in
// flight; k>=256 tail from fine_features. Same granule-XOR LDS scheme as round 5.
__global__ __launch_bounds__(256) void gemm1_kernel(
    const int* __restrict__ idx3, const float* __restrict__ w3,
    const float* __restrict__ cfT, const float* __restrict__ ff,
    const unsigned short* __restrict__ W1b, const float* __restrict__ bias,
    unsigned short* __restrict__ Y1, float* __restrict__ sums, float* __restrict__ sumsq)
{
    __shared__ __align__(16) unsigned short As[4 * 32 * 8];   // 2 KiB
    __shared__ __align__(16) unsigned short Bs[4 * 256 * 8];  // 16 KiB
    __shared__ int   sI[32][3];
    __shared__ float sWt[32][3];
    int t = threadIdx.x;
    int m0 = blockIdx.x * 32;
    int lane = t & 63, wid = t >> 6;
    int wn = wid * 64;

    if (t < 32) {
        sI[t][0]  = idx3[(m0 + t) * 3 + 0];
        sI[t][1]  = idx3[(m0 + t) * 3 + 1];
        sI[t][2]  = idx3[(m0 + t) * 3 + 2];
        sWt[t][0] = w3[(m0 + t) * 3 + 0];
        sWt[t][1] = w3[(m0 + t) * 3 + 1];
        sWt[t][2] = w3[(m0 + t) * 3 + 2];
    }
    int ksA = t & 3, rowA = t >> 2;          // A staging: threads 0..127
    int fxw = ksA << 2;
    int gA = ksA * 32 + (rowA ^ fxw);
    int rowB = t;                             // B staging: each thread one W1 row
    f32x4 acc[2][4] = {};
    int ks = lane >> 4, r16 = lane & 15, fxr = ks << 2;
    __syncthreads();

    for (int kt = 0; kt < K1; kt += 32) {
        u16x8 va;
        if (t < 128) {
            int k0 = kt + ksA * 8;
            if (k0 < DC) {
                int i0 = sI[rowA][0], i1 = sI[rowA][1], i2 = sI[rowA][2];
                float w0 = sWt[rowA][0], w1 = sWt[rowA][1], w2 = sWt[rowA][2];
                const float* c0p = &cfT[i0 * DC + k0];
                const float* c1p = &cfT[i1 * DC + k0];
                const float* c2p = &cfT[i2 * DC + k0];
                float4 a0 = *(const float4*)c0p, a1 = *(const float4*)(c0p + 4);
                float4 b0 = *(const float4*)c1p, b1 = *(const float4*)(c1p + 4);
                float4 e0 = *(const float4*)c2p, e1 = *(const float4*)(c2p + 4);
                va[0] = f2bf_bits(w0 * a0.x + w1 * b0.x + w2 * e0.x);
                va[1] = f2bf_bits(w0 * a0.y + w1 * b0.y + w2 * e0.y);
                va[2] = f2bf_bits(w0 * a0.z + w1 * b0.z + w2 * e0.z);
                va[3] = f2bf_bits(w0 * a0.w + w1 * b0.w + w2 * e0.w);
                va[4] = f2bf_bits(w0 * a1.x + w1 * b1.x + w2 * e1.x);
                va[5] = f2bf_bits(w0 * a1.y + w1 * b1.y + w2 * e1.y);
                va[6] = f2bf_bits(w0 * a1.z + w1 * b1.z + w2 * e1.z);
                va[7] = f2bf_bits(w0 * a1.w + w1 * b1.w + w2 * e1.w);
            } else {
                int c = k0 - DC;   // fine-feature channels c..c+7
                #pragma unroll
                for (int i = 0; i < 8; i++)
                    va[i] = f2bf_bits(ff[(c + i) * N_FINE + m0 + rowA]);
            }
        }
        u16x8 vb[4];
        #pragma unroll
        for (int kb = 0; kb < 4; kb++)
            vb[kb] = *(const u16x8*)&W1b[(size_t)rowB * K1 + kt + kb * 8];
        __syncthreads();   // previous iteration's frag reads complete
        if (t < 128) *(u16x8*)&As[gA * 8] = va;
        #pragma unroll
        for (int kb = 0; kb < 4; kb++)
            *(u16x8*)&Bs[(kb * 256 + (rowB ^ (kb << 2))) * 8] = vb[kb];
        __syncthreads();
        bf16x8 af[2], bfr[4];
        #pragma unroll
        for (int mi = 0; mi < 2; mi++)
            af[mi] = *(const bf16x8*)&As[(ks * 32 + ((mi * 16 + r16) ^ fxr)) * 8];
        #pragma unroll
        for (int nj = 0; nj < 4; nj++)
            bfr[nj] = *(const bf16x8*)&Bs[(ks * 256 + ((wn + nj * 16 + r16) ^ fxr)) * 8];
        #pragma unroll
        for (int mi = 0; mi < 2; mi++)
            #pragma unroll
            for (int nj = 0; nj < 4; nj++)
                acc[mi][nj] = __builtin_amdgcn_mfma_f32_16x16x32_bf16(af[mi], bfr[nj], acc[mi][nj], 0, 0, 0);
    }

    // epilogue: C/D layout col(n)=lane&15, row(m)=4*(lane>>4)+reg  [m89/m91]
    float sl[4] = {0.f, 0.f, 0.f, 0.f}, s2l[4] = {0.f, 0.f, 0.f, 0.f};
    #pragma unroll
    for (int nj = 0; nj < 4; nj++) {
        int n = wn + nj * 16 + r16;
        float bb = bias[n];
        #pragma unroll
        for (int mi = 0; mi < 2; mi++) {
            #pragma unroll
            for (int r = 0; r < 4; r++) {
                int m = m0 + mi * 16 + ks * 4 + r;
                float o = acc[mi][nj][r] + bb;
                Y1[(size_t)m * C1 + n] = f2bf_bits(o);
                sl[nj] += o; s2l[nj] += o * o;
            }
        }
    }
    #pragma unroll
    for (int nj = 0; nj < 4; nj++) {
        sl[nj]  += __shfl_xor(sl[nj],  16, 64);
        sl[nj]  += __shfl_xor(sl[nj],  32, 64);
        s2l[nj] += __shfl_xor(s2l[nj], 16, 64);
        s2l[nj] += __shfl_xor(s2l[nj], 32, 64);
    }
    if (lane < 16) {
        #pragma unroll
        for (int nj = 0; nj < 4; nj++) {
            atomicAdd(&sums[wn + nj * 16 + lane],  sl[nj]);
            atomicAdd(&sumsq[wn + nj * 16 + lane], s2l[nj]);
        }
    }
}

// ---------------- bf16 MFMA GEMM2 (BN1+ReLU on A, f32 out, fused stats) ----------------
// BM=128, BN=64, 256 threads = 4 waves (2M x 2N) — identical structure to round 5.
template <int KDIM, int NOUT>
__global__ __launch_bounds__(256) void mfma_gemm2_kernel(
    const unsigned short* __restrict__ A,   // [M][KDIM] bf16 bits
    const unsigned short* __restrict__ B,   // [NOUT][KDIM] bf16 bits
    const float* __restrict__ bias,
    const float* __restrict__ scale,
    const float* __restrict__ shift,
    float* __restrict__ Yout,
    float* __restrict__ sums, float* __restrict__ sumsq)
{
    __shared__ __align__(16) unsigned short As[4 * 128 * 8];  // 8 KiB
    __shared__ __align__(16) unsigned short Bs[4 * 64 * 8];   // 4 KiB
    int t = threadIdx.x;
    int m0 = blockIdx.x * 128, j0 = blockIdx.y * 64;
    int lane = t & 63, wid = t >> 6;
    int wm = (wid >> 1) * 64, wn = (wid & 1) * 32;

    int ksA = t & 3;
    int rowA0 = t >> 2;
    int rowA1 = 64 + rowA0;
    int fxw = ksA << 2;
    int gA0 = ksA * 128 + (rowA0 ^ fxw);
    int gA1 = ksA * 128 + (rowA1 ^ fxw);
    int gB  = ksA * 64 + (rowA0 ^ fxw);
    const unsigned short* pa0 = A + (size_t)(m0 + rowA0) * KDIM + ksA * 8;
    const unsigned short* pa1 = A + (size_t)(m0 + rowA1) * KDIM + ksA * 8;
    const unsigned short* pb  = B + (size_t)(j0 + rowA0) * KDIM + ksA * 8;

    f32x4 acc[4][2] = {};
    int ks = lane >> 4, r16 = lane & 15;
    int fxr = ks << 2;

    for (int kt = 0; kt < KDIM; kt += 32) {
        u16x8 va0 = *(const u16x8*)(pa0 + kt);
        u16x8 va1 = *(const u16x8*)(pa1 + kt);
        u16x8 vb  = *(const u16x8*)(pb + kt);
        int kb = kt + ksA * 8;
        #pragma unroll
        for (int i = 0; i < 8; i++) {
            float sc = scale[kb + i], sh = shift[kb + i];
            float f0 = __uint_as_float(((unsigned)va0[i]) << 16);
            float f1 = __uint_as_float(((unsigned)va1[i]) << 16);
            va0[i] = f2bf_bits(fmaxf(fmaf(f0, sc, sh), 0.f));
            va1[i] = f2bf_bits(fmaxf(fmaf(f1, sc, sh), 0.f));
        }
        __syncthreads();
        *(u16x8*)&As[gA0 * 8] = va0;
        *(u16x8*)&As[gA1 * 8] = va1;
        *(u16x8*)&Bs[gB * 8]  = vb;
        __syncthreads();
        bf16x8 af[4], bfr[2];
        #pragma unroll
        for (int mi = 0; mi < 4; mi++)
            af[mi] = *(const bf16x8*)&As[(ks * 128 + wm + mi * 16 + (r16 ^ fxr)) * 8];
        #pragma unroll
        for (int nj = 0; nj < 2; nj++)
            bfr[nj] = *(const bf16x8*)&Bs[(ks * 64 + wn + nj * 16 + (r16 ^ fxr)) * 8];
        #pragma unroll
        for (int mi = 0; mi < 4; mi++)
            #pragma unroll
            for (int nj = 0; nj < 2; nj++)
                acc[mi][nj] = __builtin_amdgcn_mfma_f32_16x16x32_bf16(af[mi], bfr[nj], acc[mi][nj], 0, 0, 0);
    }

    float sl[2] = {0.f, 0.f}, s2l[2] = {0.f, 0.f};
    #pragma unroll
    for (int nj = 0; nj < 2; nj++) {
        int n = j0 + wn + nj * 16 + r16;
        float bb = bias[n];
        #pragma unroll
        for (int mi = 0; mi < 4; mi++) {
            #pragma unroll
            for (int r = 0; r < 4; r++) {
                int m = m0 + wm + mi * 16 + ks * 4 + r;
                float o = acc[mi][nj][r] + bb;
                Yout[(size_t)m * NOUT + n] = o;
                sl[nj] += o; s2l[nj] += o * o;
            }
        }
    }
    #pragma unroll
    for (int nj = 0; nj < 2; nj++) {
        sl[nj]  += __shfl_xor(sl[nj],  16, 64);
        sl[nj]  += __shfl_xor(sl[nj],  32, 64);
        s2l[nj] += __shfl_xor(s2l[nj], 16, 64);
        s2l[nj] += __shfl_xor(s2l[nj], 32, 64);
    }
    if (lane < 16) {
        atomicAdd(&sums[j0 + wn + lane],       sl[0]);
        atomicAdd(&sums[j0 + wn + 16 + lane],  sl[1]);
        atomicAdd(&sumsq[j0 + wn + lane],      s2l[0]);
        atomicAdd(&sumsq[j0 + wn + 16 + lane], s2l[1]);
    }
}

__global__ void finalize_kernel(const float* __restrict__ sums, const float* __restrict__ sumsq,
                                const float* __restrict__ g, const float* __restrict__ be,
                                float* __restrict__ scale, float* __restrict__ shift, int C) {
    int t = threadIdx.x;
    if (t < C) {
        float mean = sums[t] * (1.0f / N_FINE);
        float var = sumsq[t] * (1.0f / N_FINE) - mean * mean;
        float sc = g[t] * rsqrtf(var + EPS_BN);
        scale[t] = sc;
        shift[t] = be[t] - mean * sc;
    }
}

// ---------------- BN2+ReLU fused transposed store: out[c][n] ----------------
__global__ __launch_bounds__(256) void out_kernel(const float* __restrict__ Y2,
                                                  const float* __restrict__ scale2,
                                                  const float* __restrict__ shift2,
                                                  float* __restrict__ out) {
    __shared__ float tile[64][65];
    int t = threadIdx.x;
    int n0 = blockIdx.x * 64, c0 = blockIdx.y * 64;
    int cl = t & 63, rg = t >> 6;
    #pragma unroll
    for (int i = 0; i < 16; i++) {
        int r = rg + i * 4;
        tile[r][cl] = Y2[(n0 + r) * C2 + c0 + cl];
    }
    __syncthreads();
    #pragma unroll
    for (int i = 0; i < 16; i++) {
        int c = rg + i * 4;
        float v = fmaf(tile[cl][c], scale2[c0 + c], shift2[c0 + c]);
        out[(c0 + c) * N_FINE + n0 + cl] = fmaxf(v, 0.f);
    }
}

extern "C" void kernel_launch(void* const* d_in, const int* in_sizes, int n_in,
                              void* d_out, int out_size, void* d_ws, size_t ws_size,
                              hipStream_t stream) {
    const float* fine_xyz   = (const float*)d_in[0];
    const float* coarse_xyz = (const float*)d_in[1];
    const int*   fine_pid   = (const int*)d_in[2];
    const int*   coarse_pid = (const int*)d_in[3];
    const float* fine_feat  = (const float*)d_in[4];
    const float* coarse_feat= (const float*)d_in[5];
    const float* W1  = (const float*)d_in[6];
    const float* b1  = (const float*)d_in[7];
    const float* g1  = (const float*)d_in[8];
    const float* be1 = (const float*)d_in[9];
    const float* W2  = (const float*)d_in[10];
    const float* b2  = (const float*)d_in[11];
    const float* g2  = (const float*)d_in[12];
    const float* be2 = (const float*)d_in[13];
    float* out = (float*)d_out;

    char* ws = (char*)d_ws;
    int*    ranges = (int*)(ws + OFF_RANGES);
    float*  sums1  = (float*)(ws + OFF_SUMS);
    float*  sumsq1 = sums1 + 256;
    float*  sums2  = sums1 + 512;
    float*  sumsq2 = sums1 + 640;
    float*  scale1 = (float*)(ws + OFF_SCALE1);
    float*  shift1 = (float*)(ws + OFF_SHIFT1);
    float*  scale2 = (float*)(ws + OFF_SCALE2);
    float*  shift2 = (float*)(ws + OFF_SHIFT2);
    float4* cpack  = (float4*)(ws + OFF_CPACK);
    float*  cfT    = (float*)(ws + OFF_CFT);
    int*    idx3   = (int*)(ws + OFF_IDX3);
    float*  w3     = (float*)(ws + OFF_W3);
    unsigned short* W1b = (unsigned short*)(ws + OFF_W1B);
    unsigned short* W2b = (unsigned short*)(ws + OFF_W2B);
    unsigned short* Y1  = (unsigned short*)(ws + OFF_Y1);
    float*          Y2  = (float*)(ws + OFF_Y2);

    setup_kernel<<<1361, 256, 0, stream>>>(coarse_pid, ranges, sums1,
                                           coarse_xyz, cpack, W1, W2, W1b, W2b,
                                           coarse_feat, cfT);
    knn_kernel<<<N_FINE / 16, 256, 0, stream>>>(fine_xyz, fine_pid, cpack, ranges, idx3, w3);

    gemm1_kernel<<<N_FINE / 32, 256, 0, stream>>>(idx3, w3, cfT, fine_feat,
                                                  W1b, b1, Y1, sums1, sumsq1);
    finalize_kernel<<<1, 256, 0, stream>>>(sums1, sumsq1, g1, be1, scale1, shift1, C1);

    mfma_gemm2_kernel<C1, C2><<<dim3(N_FINE / 128, C2 / 64), 256, 0, stream>>>(
        Y1, W2b, b2, scale1, shift1, Y2, sums2, sumsq2);
    finalize_kernel<<<1, 256, 0, stream>>>(sums2, sumsq2, g2, be2, scale2, shift2, C2);

    out_kernel<<<dim3(N_FINE / 64, C2 / 64), 256, 0, stream>>>(Y2, scale2, shift2, out);
}